// Round 6
// baseline (574.783 us; speedup 1.0000x reference)
//
#include <hip/hip_runtime.h>
#include <stdint.h>

// ---------------------------------------------------------------------------
// SimpleGNN_2Layer: 2-layer GCN (PyG GCNConv semantics) on MI355X.
// Round 6: rewrite k_proj1 (was 71us: 32x redundant same-address VMEM insts +
// 128 scalar LDS reads per lane). Now: LDS-tiled — 64 nodes staged once per
// block (coalesced, XOR-swizzled xs[v][k4^(v&31)] => conflict-free b128),
// W1 staged transposed (wt[f][k4] b128 broadcast). 2 nodes x 4 cols per
// thread: per k4 = 6 ds_read_b128 + 32 FMA -> FMA-bound, ~15us predicted.
// ---------------------------------------------------------------------------

#define TPB 256
#define NBLK 512                // chunks for hist/reorder (runs ~64 edges = 256B)
#define BKT_SHIFT 10            // 1024 nodes per bucket
#define BKT_NODES 1024
#define MAXBKT 128
#define SRC_BITS 17
#define SRC_MASK 0x1FFFF

__device__ __forceinline__ int edge_at(const int* __restrict__ e, long long idx, int is64) {
    return e[is64 ? (2 * idx) : idx];            // low word holds value (<2^17)
}

// per-block edge dtype detect: int64 => odd 32-bit words of first 64 entries all 0
#define DETECT_IS64(edges)                                            \
    __shared__ int s_is64;                                            \
    if (threadIdx.x < 64) {                                           \
        int v_ = (edges)[2 * threadIdx.x + 1];                        \
        unsigned long long m_ = __ballot(v_ != 0);                    \
        if (threadIdx.x == 0) s_is64 = (m_ == 0ULL) ? 1 : 0;          \
    }

__device__ __forceinline__ void f4add(float4& a, const float4 b) {
    a.x += b.x; a.y += b.y; a.z += b.z; a.w += b.w;
}

// ---- pass A: per-chunk bucket histogram, bucket-major output ----
__global__ void k_hist(const int* __restrict__ edges, int* __restrict__ hist,
                       long long E, int nbkt) {
    __shared__ int cnt[MAXBKT];
    DETECT_IS64(edges);
    if (threadIdx.x < nbkt) cnt[threadIdx.x] = 0;
    __syncthreads();
    const int is64 = s_is64;
    const long long chunk = (E + NBLK - 1) / NBLK;
    const long long beg = (long long)blockIdx.x * chunk;
    const long long end = (beg + chunk < E) ? beg + chunk : E;
    for (long long e = beg + threadIdx.x; e < end; e += blockDim.x) {
        int d = edge_at(edges, E + e, is64);
        atomicAdd(&cnt[d >> BKT_SHIFT], 1);
    }
    __syncthreads();
    if (threadIdx.x < nbkt) hist[threadIdx.x * NBLK + blockIdx.x] = cnt[threadIdx.x];
}

// ---- pass B: reorder edges into bucket-major packed tmp (dlocal<<17|src) ----
__global__ void k_reorder(const int* __restrict__ edges, const int* __restrict__ histoff,
                          unsigned int* __restrict__ tmp, long long E, int nbkt) {
    __shared__ int off[MAXBKT];
    DETECT_IS64(edges);
    if (threadIdx.x < nbkt) off[threadIdx.x] = histoff[threadIdx.x * NBLK + blockIdx.x];
    __syncthreads();
    const int is64 = s_is64;
    const long long chunk = (E + NBLK - 1) / NBLK;
    const long long beg = (long long)blockIdx.x * chunk;
    const long long end = (beg + chunk < E) ? beg + chunk : E;
    for (long long e = beg + threadIdx.x; e < end; e += blockDim.x) {
        int s = edge_at(edges, e, is64);
        int d = edge_at(edges, E + e, is64);
        int pos = atomicAdd(&off[d >> BKT_SHIFT], 1);
        tmp[pos] = ((unsigned int)(d & (BKT_NODES - 1)) << SRC_BITS) | (unsigned int)s;
    }
}

// ---- generic scan step 1: per-block sums ----
__global__ void k_scan_partial(const int* __restrict__ cnt, int* __restrict__ partial, int N) {
    __shared__ int lds[TPB];
    int i = blockIdx.x * TPB + threadIdx.x;
    lds[threadIdx.x] = (i < N) ? cnt[i] : 0;
    __syncthreads();
    for (int s = TPB / 2; s > 0; s >>= 1) {
        if (threadIdx.x < s) lds[threadIdx.x] += lds[threadIdx.x + s];
        __syncthreads();
    }
    if (threadIdx.x == 0) partial[blockIdx.x] = lds[0];
}

// ---- generic scan step 2: exclusive scan of partials (NB <= 512) ----
__global__ void k_scan_top(int* __restrict__ partial, int NB) {
    __shared__ int lds[512];
    int t = threadIdx.x;
    int v = (t < NB) ? partial[t] : 0;
    lds[t] = v;
    __syncthreads();
    for (int off = 1; off < 512; off <<= 1) {
        int x = (t >= off) ? lds[t - off] : 0;
        __syncthreads();
        lds[t] += x;
        __syncthreads();
    }
    if (t < NB) partial[t] = lds[t] - v;   // exclusive
    if (t == 0) partial[NB] = lds[511];    // total
}

// ---- generic scan step 3: write exclusive scan (grid covers index N too) ----
__global__ void k_scan_write(const int* __restrict__ cnt, const int* __restrict__ partial,
                             int* __restrict__ outp, int N, int NB) {
    __shared__ int lds[TPB];
    int i = blockIdx.x * TPB + threadIdx.x;
    int v = (i < N) ? cnt[i] : 0;
    lds[threadIdx.x] = v;
    __syncthreads();
    for (int off = 1; off < TPB; off <<= 1) {
        int x = (threadIdx.x >= off) ? lds[threadIdx.x - off] : 0;
        __syncthreads();
        lds[threadIdx.x] += x;
        __syncthreads();
    }
    if (i < N) outp[i] = partial[blockIdx.x] + lds[threadIdx.x] - v;
    if (i == N) outp[N] = partial[NB];
}

// ---- per-bucket sort: deg count + scan + dinv/row_ptr + col placement ----
__global__ void k_sortbucket(const unsigned int* __restrict__ tmp, const int* __restrict__ histoff,
                             float* __restrict__ dinv, int* __restrict__ row_ptr,
                             int* __restrict__ col, int N, long long E, int nbkt) {
    __shared__ int scnt[BKT_NODES];
    const int t = threadIdx.x;            // 0..511
    const int b = blockIdx.x;
    const int begI = histoff[b * NBLK];
    const int endI = histoff[(b + 1) * NBLK];   // histoff[nbkt*NBLK] == E
    scnt[t] = 0; scnt[t + 512] = 0;
    __syncthreads();
    for (int e = begI + t; e < endI; e += 512)
        atomicAdd(&scnt[tmp[e] >> SRC_BITS], 1);
    __syncthreads();
    const int c0 = scnt[t], c1 = scnt[t + 512];
    for (int off = 1; off < BKT_NODES; off <<= 1) {
        int i0 = t, i1 = t + 512;
        int a0 = (i0 >= off) ? scnt[i0 - off] : 0;
        int a1 = (i1 >= off) ? scnt[i1 - off] : 0;
        __syncthreads();
        scnt[i0] += a0; scnt[i1] += a1;
        __syncthreads();
    }
    const int rp0 = begI + scnt[t] - c0;          // exclusive + bucket base
    const int rp1 = begI + scnt[t + 512] - c1;
    const int v0 = (b << BKT_SHIFT) + t;
    const int v1 = v0 + 512;
    if (v0 < N) { dinv[v0] = rsqrtf((float)(c0 + 1)); row_ptr[v0] = rp0; }
    if (v1 < N) { dinv[v1] = rsqrtf((float)(c1 + 1)); row_ptr[v1] = rp1; }
    if (b == nbkt - 1 && t == 0) row_ptr[N] = (int)E;
    __syncthreads();
    scnt[t] = rp0; scnt[t + 512] = rp1;           // running fill offsets
    __syncthreads();
    for (int e = begI + t; e < endI; e += 512) {
        unsigned int p = tmp[e];
        int pos = atomicAdd(&scnt[p >> SRC_BITS], 1);
        col[pos] = (int)(p & SRC_MASK);
    }
}

// ---- proj1: h1s[v] = (x[v] @ W1) * dinv[v]   (128 -> 32), LDS-tiled ----
// 64 nodes/block. xs[v][k4^(v&31)] XOR-swizzle => conflict-free b128 reads.
// wt = W1^T as float4 rows: wt[f][k4]. Thread: nodes (ng, ng+32) x cols f4*4..+3.
__global__ __launch_bounds__(TPB) void k_proj1(const float* __restrict__ x,
                        const float* __restrict__ W1, const float* __restrict__ dinv,
                        float* __restrict__ h1s, int N) {
    __shared__ float4 xs[64 * 32];   // 32KB
    __shared__ float4 wt[32 * 32];   // 16KB  (W1T: wt[f*32+k4][c] = W1[(4k4+c)*32+f])
    const int t = threadIdx.x;
    const int vbase = blockIdx.x * 64;
    // stage W1 transposed (scalar writes, bank-spread; W1 is 16KB, L2-resident)
    for (int idx = t; idx < 4096; idx += TPB) {
        int k = idx & 127, f = idx >> 7;
        ((float*)wt)[f * 128 + k] = W1[k * 32 + f];
    }
    // stage x tile: coalesced global float4, XOR-swizzled LDS write
    for (int idx = t; idx < 64 * 32; idx += TPB) {
        int v = idx >> 5, k4 = idx & 31;
        int vg = vbase + v;
        float4 val = (vg < N) ? *(const float4*)(x + (long long)vg * 128 + k4 * 4)
                              : make_float4(0.f, 0.f, 0.f, 0.f);
        xs[v * 32 + (k4 ^ (v & 31))] = val;
    }
    __syncthreads();
    const int ng = t & 31;           // node within half-tile
    const int f4 = t >> 5;           // col group (0..7): cols f4*4..f4*4+3
    float4 acc0 = make_float4(0.f, 0.f, 0.f, 0.f);
    float4 acc1 = make_float4(0.f, 0.f, 0.f, 0.f);
#pragma unroll
    for (int k4 = 0; k4 < 32; k4++) {
        float4 xv0 = xs[ng * 32 + (k4 ^ ng)];           // x[v0][4k4..+3]
        float4 xv1 = xs[(ng + 32) * 32 + (k4 ^ ng)];    // x[v1][4k4..+3]
        float4 w0 = wt[(f4 * 4 + 0) * 32 + k4];
        float4 w1 = wt[(f4 * 4 + 1) * 32 + k4];
        float4 w2 = wt[(f4 * 4 + 2) * 32 + k4];
        float4 w3 = wt[(f4 * 4 + 3) * 32 + k4];
        acc0.x = fmaf(xv0.x, w0.x, acc0.x); acc0.x = fmaf(xv0.y, w0.y, acc0.x);
        acc0.x = fmaf(xv0.z, w0.z, acc0.x); acc0.x = fmaf(xv0.w, w0.w, acc0.x);
        acc0.y = fmaf(xv0.x, w1.x, acc0.y); acc0.y = fmaf(xv0.y, w1.y, acc0.y);
        acc0.y = fmaf(xv0.z, w1.z, acc0.y); acc0.y = fmaf(xv0.w, w1.w, acc0.y);
        acc0.z = fmaf(xv0.x, w2.x, acc0.z); acc0.z = fmaf(xv0.y, w2.y, acc0.z);
        acc0.z = fmaf(xv0.z, w2.z, acc0.z); acc0.z = fmaf(xv0.w, w2.w, acc0.z);
        acc0.w = fmaf(xv0.x, w3.x, acc0.w); acc0.w = fmaf(xv0.y, w3.y, acc0.w);
        acc0.w = fmaf(xv0.z, w3.z, acc0.w); acc0.w = fmaf(xv0.w, w3.w, acc0.w);
        acc1.x = fmaf(xv1.x, w0.x, acc1.x); acc1.x = fmaf(xv1.y, w0.y, acc1.x);
        acc1.x = fmaf(xv1.z, w0.z, acc1.x); acc1.x = fmaf(xv1.w, w0.w, acc1.x);
        acc1.y = fmaf(xv1.x, w1.x, acc1.y); acc1.y = fmaf(xv1.y, w1.y, acc1.y);
        acc1.y = fmaf(xv1.z, w1.z, acc1.y); acc1.y = fmaf(xv1.w, w1.w, acc1.y);
        acc1.z = fmaf(xv1.x, w2.x, acc1.z); acc1.z = fmaf(xv1.y, w2.y, acc1.z);
        acc1.z = fmaf(xv1.z, w2.z, acc1.z); acc1.z = fmaf(xv1.w, w2.w, acc1.z);
        acc1.w = fmaf(xv1.x, w3.x, acc1.w); acc1.w = fmaf(xv1.y, w3.y, acc1.w);
        acc1.w = fmaf(xv1.z, w3.z, acc1.w); acc1.w = fmaf(xv1.w, w3.w, acc1.w);
    }
    const int v0 = vbase + ng, v1 = v0 + 32;
    if (v0 < N) {
        float dv = dinv[v0];
        acc0.x *= dv; acc0.y *= dv; acc0.z *= dv; acc0.w *= dv;
        *(float4*)(h1s + (long long)v0 * 32 + f4 * 4) = acc0;
    }
    if (v1 < N) {
        float dv = dinv[v1];
        acc1.x *= dv; acc1.y *= dv; acc1.z *= dv; acc1.w *= dv;
        *(float4*)(h1s + (long long)v1 * 32 + f4 * 4) = acc1;
    }
}

// ---- gather1: out1[v] = relu(dinv[v]*(h1s[v] + sum_in h1s[u]) + b1) ----
// 32 lanes/node = 4 neighbor-slots x 8 float4-lanes; unroll 2 -> 16 lines in flight/wave
__global__ void k_gather1(const float* __restrict__ h1s, const int* __restrict__ col,
                          const int* __restrict__ rp, const float* __restrict__ dinv,
                          const float* __restrict__ b1, float* __restrict__ out1, int N) {
    int t = blockIdx.x * TPB + threadIdx.x;
    int v = t >> 5;
    if (v >= N) return;
    int l32 = threadIdx.x & 31;
    int slot = l32 >> 3;                 // 0..3
    int f4 = l32 & 7;                    // features f4*4 .. f4*4+3
    int beg = rp[v], end = rp[v + 1];
    float4 s0 = make_float4(0.f, 0.f, 0.f, 0.f);
    float4 s1 = make_float4(0.f, 0.f, 0.f, 0.f);
    if (slot == 0)                        // self loop
        s0 = *(const float4*)(h1s + (long long)v * 32 + f4 * 4);
    int i = beg + slot;
    for (; i + 4 < end; i += 8) {
        int u0 = col[i], u1 = col[i + 4];
        float4 a = *(const float4*)(h1s + (long long)u0 * 32 + f4 * 4);
        float4 b = *(const float4*)(h1s + (long long)u1 * 32 + f4 * 4);
        f4add(s0, a);
        f4add(s1, b);
    }
    if (i < end) {
        int u0 = col[i];
        float4 a = *(const float4*)(h1s + (long long)u0 * 32 + f4 * 4);
        f4add(s0, a);
    }
    f4add(s0, s1);
    s0.x += __shfl_xor(s0.x, 8);  s0.y += __shfl_xor(s0.y, 8);
    s0.z += __shfl_xor(s0.z, 8);  s0.w += __shfl_xor(s0.w, 8);
    s0.x += __shfl_xor(s0.x, 16); s0.y += __shfl_xor(s0.y, 16);
    s0.z += __shfl_xor(s0.z, 16); s0.w += __shfl_xor(s0.w, 16);
    if (slot == 0) {
        float dv = dinv[v];
        float4 bb = *(const float4*)(b1 + f4 * 4);
        float4 r;
        r.x = dv * s0.x + bb.x; r.x = r.x > 0.f ? r.x : 0.f;
        r.y = dv * s0.y + bb.y; r.y = r.y > 0.f ? r.y : 0.f;
        r.z = dv * s0.z + bb.z; r.z = r.z > 0.f ? r.z : 0.f;
        r.w = dv * s0.w + bb.w; r.w = r.w > 0.f ? r.w : 0.f;
        *(float4*)(out1 + (long long)v * 32 + f4 * 4) = r;   // 8 lanes x 16B = 128B
    }
}

// ---- proj2: h2s[v] = (out1[v] @ W2) * dinv[v]   (32 -> 16) ----
__global__ void k_proj2(const float* __restrict__ out1, const float* __restrict__ W2,
                        const float* __restrict__ dinv, float* __restrict__ h2s, int N) {
    __shared__ float w[32 * 16];
    for (int i = threadIdx.x; i < 32 * 16; i += TPB) w[i] = W2[i];
    __syncthreads();
    int t = blockIdx.x * TPB + threadIdx.x;
    int v = t >> 4, f = t & 15;
    if (v >= N) return;
    const float4* xr = (const float4*)(out1 + (long long)v * 32);
    float acc = 0.f;
#pragma unroll
    for (int k4 = 0; k4 < 8; k4++) {
        float4 xv = xr[k4];
        int k = k4 * 4;
        acc = fmaf(xv.x, w[(k + 0) * 16 + f], acc);
        acc = fmaf(xv.y, w[(k + 1) * 16 + f], acc);
        acc = fmaf(xv.z, w[(k + 2) * 16 + f], acc);
        acc = fmaf(xv.w, w[(k + 3) * 16 + f], acc);
    }
    h2s[(long long)v * 16 + f] = acc * dinv[v];
}

// ---- gather2 + relu + final dot with Wl, bias bl ----
__global__ void k_gather2(const float* __restrict__ h2s, const int* __restrict__ col,
                          const int* __restrict__ rp, const float* __restrict__ dinv,
                          const float* __restrict__ b2, const float* __restrict__ Wl,
                          const float* __restrict__ bl, float* __restrict__ out, int N) {
    int t = blockIdx.x * TPB + threadIdx.x;
    int v = t >> 5;
    if (v >= N) return;
    int l32 = threadIdx.x & 31;
    int slot = l32 >> 2;                 // 0..7
    int f4 = l32 & 3;                    // features f4*4 .. f4*4+3
    int beg = rp[v], end = rp[v + 1];
    float4 s = make_float4(0.f, 0.f, 0.f, 0.f);
    if (slot == 0)                        // self loop
        s = *(const float4*)(h2s + (long long)v * 16 + f4 * 4);
    for (int i = beg + slot; i < end; i += 8) {
        int u = col[i];
        float4 a = *(const float4*)(h2s + (long long)u * 16 + f4 * 4);
        f4add(s, a);
    }
    s.x += __shfl_xor(s.x, 4);  s.y += __shfl_xor(s.y, 4);
    s.z += __shfl_xor(s.z, 4);  s.w += __shfl_xor(s.w, 4);
    s.x += __shfl_xor(s.x, 8);  s.y += __shfl_xor(s.y, 8);
    s.z += __shfl_xor(s.z, 8);  s.w += __shfl_xor(s.w, 8);
    s.x += __shfl_xor(s.x, 16); s.y += __shfl_xor(s.y, 16);
    s.z += __shfl_xor(s.z, 16); s.w += __shfl_xor(s.w, 16);
    if (slot == 0) {
        float dv = dinv[v];
        float4 bb = *(const float4*)(b2 + f4 * 4);
        float4 wl = *(const float4*)(Wl + f4 * 4);
        float rx = dv * s.x + bb.x; rx = rx > 0.f ? rx : 0.f;
        float ry = dv * s.y + bb.y; ry = ry > 0.f ? ry : 0.f;
        float rz = dv * s.z + bb.z; rz = rz > 0.f ? rz : 0.f;
        float rw = dv * s.w + bb.w; rw = rw > 0.f ? rw : 0.f;
        float p = rx * wl.x + ry * wl.y + rz * wl.z + rw * wl.w;
        p += __shfl_xor(p, 1);
        p += __shfl_xor(p, 2);
        if (f4 == 0) out[v] = p + bl[0];
    }
}

// ---------------------------------------------------------------------------
extern "C" void kernel_launch(void* const* d_in, const int* in_sizes, int n_in,
                              void* d_out, int out_size, void* d_ws, size_t ws_size,
                              hipStream_t stream) {
    const float* x    = (const float*)d_in[0];
    const int*   edges= (const int*)d_in[1];     // int32 or int64(low-word) — autodetected
    const float* W1   = (const float*)d_in[2];
    const float* b1   = (const float*)d_in[3];
    const float* W2   = (const float*)d_in[4];
    const float* b2   = (const float*)d_in[5];
    const float* Wl   = (const float*)d_in[6];
    const float* bl   = (const float*)d_in[7];
    float* out = (float*)d_out;

    const int       N = in_sizes[0] / 128;          // 100000
    const long long E = (long long)in_sizes[1] / 2; // 3200000
    const int    nbkt = (N + BKT_NODES - 1) >> BKT_SHIFT;  // 98 (<=MAXBKT)
    const int      NH = nbkt * NBLK;                // 50176
    const int    NB_H = (NH + TPB - 1) / TPB;       // 196 (<=512 for scan_top)

    // workspace layout (256B aligned slices); tmp aliases h1s region
    char* ws = (char*)d_ws;
    size_t off = 0;
    auto carve = [&](size_t bytes) { void* p = ws + off; off = (off + bytes + 255) & ~(size_t)255; return p; };
    float* dinv    = (float*)carve((size_t)N * 4);
    int*   row_ptr = (int*)  carve((size_t)(N + 1) * 4);
    int*   partialH= (int*)  carve((size_t)(NB_H + 1) * 4);
    int*   hist    = (int*)  carve((size_t)NH * 4);
    int*   histoff = (int*)  carve((size_t)(NH + 1) * 4);
    int*   col     = (int*)  carve((size_t)E * 4);
    float* unionA  = (float*)carve((size_t)N * 64 * 4);  // h1s(32)+out1(32) / packed tmp(E)
    float* h2s     = (float*)carve((size_t)N * 16 * 4);
    (void)ws_size; // total ~46 MB

    float*        h1s  = unionA;                  // N*32 floats
    float*        out1 = unionA + (size_t)N * 32;
    unsigned int* tmp  = (unsigned int*)unionA;   // E u32 (= N*32*4 bytes), dead before proj1

    // ---- binned CSR build ----
    hipLaunchKernelGGL(k_hist, dim3(NBLK), dim3(TPB), 0, stream, edges, hist, E, nbkt);
    hipLaunchKernelGGL(k_scan_partial, dim3(NB_H), dim3(TPB), 0, stream, hist, partialH, NH);
    hipLaunchKernelGGL(k_scan_top, dim3(1), dim3(512), 0, stream, partialH, NB_H);
    hipLaunchKernelGGL(k_scan_write, dim3(NB_H + 1), dim3(TPB), 0, stream, hist, partialH, histoff, NH, NB_H);
    hipLaunchKernelGGL(k_reorder, dim3(NBLK), dim3(TPB), 0, stream, edges, histoff, tmp, E, nbkt);
    hipLaunchKernelGGL(k_sortbucket, dim3(nbkt), dim3(512), 0, stream, tmp, histoff, dinv, row_ptr, col, N, E, nbkt);
    // ---- layer 1 (h1s/out1 reuse tmp region — tmp dead after sortbucket) ----
    hipLaunchKernelGGL(k_proj1, dim3((N + 63) / 64), dim3(TPB), 0, stream, x, W1, dinv, h1s, N);
    hipLaunchKernelGGL(k_gather1, dim3((N * 32 + TPB - 1) / TPB), dim3(TPB), 0, stream, h1s, col, row_ptr, dinv, b1, out1, N);
    // ---- layer 2 + head ----
    hipLaunchKernelGGL(k_proj2, dim3((N * 16 + TPB - 1) / TPB), dim3(TPB), 0, stream, out1, W2, dinv, h2s, N);
    hipLaunchKernelGGL(k_gather2, dim3((N * 32 + TPB - 1) / TPB), dim3(TPB), 0, stream, h2s, col, row_ptr, dinv, b2, Wl, bl, out, N);
}

// Round 7
// 312.134 us; speedup vs baseline: 1.8415x; 1.8415x over previous
//
#include <hip/hip_runtime.h>
#include <stdint.h>

// ---------------------------------------------------------------------------
// SimpleGNN_2Layer: 2-layer GCN (PyG GCNConv semantics) on MI355X.
// Round 7: un-regress proj1 (round 6 spilled: 256 VGPR, 10% occ, 500MB
// scratch traffic). New proj design: lane=node, x tile in LDS (XOR-swizzled,
// conflict-free), W read via readfirstlane-uniform scalar loads (s_load,
// scalar cache) -> ~40 VGPR, no spills, memory-bound as it should be.
// ---------------------------------------------------------------------------

#define TPB 256
#define NBLK 512                // chunks for hist/reorder (runs ~64 edges = 256B)
#define BKT_SHIFT 10            // 1024 nodes per bucket
#define BKT_NODES 1024
#define MAXBKT 128
#define SRC_BITS 17
#define SRC_MASK 0x1FFFF

__device__ __forceinline__ int edge_at(const int* __restrict__ e, long long idx, int is64) {
    return e[is64 ? (2 * idx) : idx];            // low word holds value (<2^17)
}

// per-block edge dtype detect: int64 => odd 32-bit words of first 64 entries all 0
#define DETECT_IS64(edges)                                            \
    __shared__ int s_is64;                                            \
    if (threadIdx.x < 64) {                                           \
        int v_ = (edges)[2 * threadIdx.x + 1];                        \
        unsigned long long m_ = __ballot(v_ != 0);                    \
        if (threadIdx.x == 0) s_is64 = (m_ == 0ULL) ? 1 : 0;          \
    }

__device__ __forceinline__ void f4add(float4& a, const float4 b) {
    a.x += b.x; a.y += b.y; a.z += b.z; a.w += b.w;
}

// ---- pass A: per-chunk bucket histogram, bucket-major output ----
__global__ void k_hist(const int* __restrict__ edges, int* __restrict__ hist,
                       long long E, int nbkt) {
    __shared__ int cnt[MAXBKT];
    DETECT_IS64(edges);
    if (threadIdx.x < nbkt) cnt[threadIdx.x] = 0;
    __syncthreads();
    const int is64 = s_is64;
    const long long chunk = (E + NBLK - 1) / NBLK;
    const long long beg = (long long)blockIdx.x * chunk;
    const long long end = (beg + chunk < E) ? beg + chunk : E;
    for (long long e = beg + threadIdx.x; e < end; e += blockDim.x) {
        int d = edge_at(edges, E + e, is64);
        atomicAdd(&cnt[d >> BKT_SHIFT], 1);
    }
    __syncthreads();
    if (threadIdx.x < nbkt) hist[threadIdx.x * NBLK + blockIdx.x] = cnt[threadIdx.x];
}

// ---- pass B: reorder edges into bucket-major packed tmp (dlocal<<17|src) ----
__global__ void k_reorder(const int* __restrict__ edges, const int* __restrict__ histoff,
                          unsigned int* __restrict__ tmp, long long E, int nbkt) {
    __shared__ int off[MAXBKT];
    DETECT_IS64(edges);
    if (threadIdx.x < nbkt) off[threadIdx.x] = histoff[threadIdx.x * NBLK + blockIdx.x];
    __syncthreads();
    const int is64 = s_is64;
    const long long chunk = (E + NBLK - 1) / NBLK;
    const long long beg = (long long)blockIdx.x * chunk;
    const long long end = (beg + chunk < E) ? beg + chunk : E;
    for (long long e = beg + threadIdx.x; e < end; e += blockDim.x) {
        int s = edge_at(edges, e, is64);
        int d = edge_at(edges, E + e, is64);
        int pos = atomicAdd(&off[d >> BKT_SHIFT], 1);
        tmp[pos] = ((unsigned int)(d & (BKT_NODES - 1)) << SRC_BITS) | (unsigned int)s;
    }
}

// ---- generic scan step 1: per-block sums ----
__global__ void k_scan_partial(const int* __restrict__ cnt, int* __restrict__ partial, int N) {
    __shared__ int lds[TPB];
    int i = blockIdx.x * TPB + threadIdx.x;
    lds[threadIdx.x] = (i < N) ? cnt[i] : 0;
    __syncthreads();
    for (int s = TPB / 2; s > 0; s >>= 1) {
        if (threadIdx.x < s) lds[threadIdx.x] += lds[threadIdx.x + s];
        __syncthreads();
    }
    if (threadIdx.x == 0) partial[blockIdx.x] = lds[0];
}

// ---- generic scan step 2: exclusive scan of partials (NB <= 512) ----
__global__ void k_scan_top(int* __restrict__ partial, int NB) {
    __shared__ int lds[512];
    int t = threadIdx.x;
    int v = (t < NB) ? partial[t] : 0;
    lds[t] = v;
    __syncthreads();
    for (int off = 1; off < 512; off <<= 1) {
        int x = (t >= off) ? lds[t - off] : 0;
        __syncthreads();
        lds[t] += x;
        __syncthreads();
    }
    if (t < NB) partial[t] = lds[t] - v;   // exclusive
    if (t == 0) partial[NB] = lds[511];    // total
}

// ---- generic scan step 3: write exclusive scan (grid covers index N too) ----
__global__ void k_scan_write(const int* __restrict__ cnt, const int* __restrict__ partial,
                             int* __restrict__ outp, int N, int NB) {
    __shared__ int lds[TPB];
    int i = blockIdx.x * TPB + threadIdx.x;
    int v = (i < N) ? cnt[i] : 0;
    lds[threadIdx.x] = v;
    __syncthreads();
    for (int off = 1; off < TPB; off <<= 1) {
        int x = (threadIdx.x >= off) ? lds[threadIdx.x - off] : 0;
        __syncthreads();
        lds[threadIdx.x] += x;
        __syncthreads();
    }
    if (i < N) outp[i] = partial[blockIdx.x] + lds[threadIdx.x] - v;
    if (i == N) outp[N] = partial[NB];
}

// ---- per-bucket sort: deg count + scan + dinv/row_ptr + col placement ----
__global__ void k_sortbucket(const unsigned int* __restrict__ tmp, const int* __restrict__ histoff,
                             float* __restrict__ dinv, int* __restrict__ row_ptr,
                             int* __restrict__ col, int N, long long E, int nbkt) {
    __shared__ int scnt[BKT_NODES];
    const int t = threadIdx.x;            // 0..511
    const int b = blockIdx.x;
    const int begI = histoff[b * NBLK];
    const int endI = histoff[(b + 1) * NBLK];   // histoff[nbkt*NBLK] == E
    scnt[t] = 0; scnt[t + 512] = 0;
    __syncthreads();
    for (int e = begI + t; e < endI; e += 512)
        atomicAdd(&scnt[tmp[e] >> SRC_BITS], 1);
    __syncthreads();
    const int c0 = scnt[t], c1 = scnt[t + 512];
    for (int off = 1; off < BKT_NODES; off <<= 1) {
        int i0 = t, i1 = t + 512;
        int a0 = (i0 >= off) ? scnt[i0 - off] : 0;
        int a1 = (i1 >= off) ? scnt[i1 - off] : 0;
        __syncthreads();
        scnt[i0] += a0; scnt[i1] += a1;
        __syncthreads();
    }
    const int rp0 = begI + scnt[t] - c0;          // exclusive + bucket base
    const int rp1 = begI + scnt[t + 512] - c1;
    const int v0 = (b << BKT_SHIFT) + t;
    const int v1 = v0 + 512;
    if (v0 < N) { dinv[v0] = rsqrtf((float)(c0 + 1)); row_ptr[v0] = rp0; }
    if (v1 < N) { dinv[v1] = rsqrtf((float)(c1 + 1)); row_ptr[v1] = rp1; }
    if (b == nbkt - 1 && t == 0) row_ptr[N] = (int)E;
    __syncthreads();
    scnt[t] = rp0; scnt[t + 512] = rp1;           // running fill offsets
    __syncthreads();
    for (int e = begI + t; e < endI; e += 512) {
        unsigned int p = tmp[e];
        int pos = atomicAdd(&scnt[p >> SRC_BITS], 1);
        col[pos] = (int)(p & SRC_MASK);
    }
}

// ---- proj1: h1s[v] = (x[v] @ W1) * dinv[v]  (128 -> 32) ----
// lane = node (64/wave), wave = 8 cols. x tile in LDS (swizzled, conflict-free
// b128); W1 via readfirstlane-uniform s_load (scalar cache). ~40 VGPR.
__global__ __launch_bounds__(TPB) void k_proj1(const float* __restrict__ x,
                        const float* __restrict__ W1, const float* __restrict__ dinv,
                        float* __restrict__ h1s, int N) {
    __shared__ float4 xs[64 * 32];   // 32KB: xs[v][k4 ^ (v&31)]
    const int t = threadIdx.x;
    const int vbase = blockIdx.x * 64;
    for (int idx = t; idx < 64 * 32; idx += TPB) {
        int v = idx >> 5, k4 = idx & 31;
        int vg = vbase + v;
        float4 val = (vg < N) ? *(const float4*)(x + (long long)vg * 128 + k4 * 4)
                              : make_float4(0.f, 0.f, 0.f, 0.f);
        xs[v * 32 + (k4 ^ (v & 31))] = val;
    }
    __syncthreads();
    const int l = t & 63;                                          // node lane
    const int cb = __builtin_amdgcn_readfirstlane((t >> 6) * 8);   // col base 0/8/16/24
    float acc[8] = {0.f, 0.f, 0.f, 0.f, 0.f, 0.f, 0.f, 0.f};
#pragma unroll 4
    for (int k4 = 0; k4 < 32; k4++) {
        float4 xv = xs[l * 32 + (k4 ^ (l & 31))];
#pragma unroll
        for (int j = 0; j < 4; j++) {
            const float* wr = W1 + (k4 * 4 + j) * 32 + cb;         // uniform -> s_load
            float4 wa = *(const float4*)(wr);
            float4 wb = *(const float4*)(wr + 4);
            float xj = (j == 0) ? xv.x : (j == 1) ? xv.y : (j == 2) ? xv.z : xv.w;
            acc[0] = fmaf(xj, wa.x, acc[0]); acc[1] = fmaf(xj, wa.y, acc[1]);
            acc[2] = fmaf(xj, wa.z, acc[2]); acc[3] = fmaf(xj, wa.w, acc[3]);
            acc[4] = fmaf(xj, wb.x, acc[4]); acc[5] = fmaf(xj, wb.y, acc[5]);
            acc[6] = fmaf(xj, wb.z, acc[6]); acc[7] = fmaf(xj, wb.w, acc[7]);
        }
    }
    const int v = vbase + l;
    if (v < N) {
        float dv = dinv[v];
        *(float4*)(h1s + (long long)v * 32 + cb) =
            make_float4(acc[0] * dv, acc[1] * dv, acc[2] * dv, acc[3] * dv);
        *(float4*)(h1s + (long long)v * 32 + cb + 4) =
            make_float4(acc[4] * dv, acc[5] * dv, acc[6] * dv, acc[7] * dv);
    }
}

// ---- gather1: out1[v] = relu(dinv[v]*(h1s[v] + sum_in h1s[u]) + b1) ----
// 32 lanes/node = 4 neighbor-slots x 8 float4-lanes; unroll 2 -> 16 lines in flight/wave
__global__ void k_gather1(const float* __restrict__ h1s, const int* __restrict__ col,
                          const int* __restrict__ rp, const float* __restrict__ dinv,
                          const float* __restrict__ b1, float* __restrict__ out1, int N) {
    int t = blockIdx.x * TPB + threadIdx.x;
    int v = t >> 5;
    if (v >= N) return;
    int l32 = threadIdx.x & 31;
    int slot = l32 >> 3;                 // 0..3
    int f4 = l32 & 7;                    // features f4*4 .. f4*4+3
    int beg = rp[v], end = rp[v + 1];
    float4 s0 = make_float4(0.f, 0.f, 0.f, 0.f);
    float4 s1 = make_float4(0.f, 0.f, 0.f, 0.f);
    if (slot == 0)                        // self loop
        s0 = *(const float4*)(h1s + (long long)v * 32 + f4 * 4);
    int i = beg + slot;
    for (; i + 4 < end; i += 8) {
        int u0 = col[i], u1 = col[i + 4];
        float4 a = *(const float4*)(h1s + (long long)u0 * 32 + f4 * 4);
        float4 b = *(const float4*)(h1s + (long long)u1 * 32 + f4 * 4);
        f4add(s0, a);
        f4add(s1, b);
    }
    if (i < end) {
        int u0 = col[i];
        float4 a = *(const float4*)(h1s + (long long)u0 * 32 + f4 * 4);
        f4add(s0, a);
    }
    f4add(s0, s1);
    s0.x += __shfl_xor(s0.x, 8);  s0.y += __shfl_xor(s0.y, 8);
    s0.z += __shfl_xor(s0.z, 8);  s0.w += __shfl_xor(s0.w, 8);
    s0.x += __shfl_xor(s0.x, 16); s0.y += __shfl_xor(s0.y, 16);
    s0.z += __shfl_xor(s0.z, 16); s0.w += __shfl_xor(s0.w, 16);
    if (slot == 0) {
        float dv = dinv[v];
        float4 bb = *(const float4*)(b1 + f4 * 4);
        float4 r;
        r.x = dv * s0.x + bb.x; r.x = r.x > 0.f ? r.x : 0.f;
        r.y = dv * s0.y + bb.y; r.y = r.y > 0.f ? r.y : 0.f;
        r.z = dv * s0.z + bb.z; r.z = r.z > 0.f ? r.z : 0.f;
        r.w = dv * s0.w + bb.w; r.w = r.w > 0.f ? r.w : 0.f;
        *(float4*)(out1 + (long long)v * 32 + f4 * 4) = r;   // 8 lanes x 16B = 128B
    }
}

// ---- proj2: h2s[v] = (out1[v] @ W2) * dinv[v]  (32 -> 16) ----
// same scalar-W design: lane = node, wave = 4 cols, out1 tile in LDS (8KB).
__global__ __launch_bounds__(TPB) void k_proj2(const float* __restrict__ out1,
                        const float* __restrict__ W2, const float* __restrict__ dinv,
                        float* __restrict__ h2s, int N) {
    __shared__ float4 xs[64 * 8];    // 8KB: xs[v][k4 ^ (v&7)]
    const int t = threadIdx.x;
    const int vbase = blockIdx.x * 64;
    for (int idx = t; idx < 64 * 8; idx += TPB) {
        int v = idx >> 3, k4 = idx & 7;
        int vg = vbase + v;
        float4 val = (vg < N) ? *(const float4*)(out1 + (long long)vg * 32 + k4 * 4)
                              : make_float4(0.f, 0.f, 0.f, 0.f);
        xs[v * 8 + (k4 ^ (v & 7))] = val;
    }
    __syncthreads();
    const int l = t & 63;
    const int cb = __builtin_amdgcn_readfirstlane((t >> 6) * 4);   // col base 0/4/8/12
    float acc[4] = {0.f, 0.f, 0.f, 0.f};
#pragma unroll
    for (int k4 = 0; k4 < 8; k4++) {
        float4 xv = xs[l * 8 + (k4 ^ (l & 7))];
#pragma unroll
        for (int j = 0; j < 4; j++) {
            float4 w4 = *(const float4*)(W2 + (k4 * 4 + j) * 16 + cb);  // uniform
            float xj = (j == 0) ? xv.x : (j == 1) ? xv.y : (j == 2) ? xv.z : xv.w;
            acc[0] = fmaf(xj, w4.x, acc[0]); acc[1] = fmaf(xj, w4.y, acc[1]);
            acc[2] = fmaf(xj, w4.z, acc[2]); acc[3] = fmaf(xj, w4.w, acc[3]);
        }
    }
    const int v = vbase + l;
    if (v < N) {
        float dv = dinv[v];
        *(float4*)(h2s + (long long)v * 16 + cb) =
            make_float4(acc[0] * dv, acc[1] * dv, acc[2] * dv, acc[3] * dv);
    }
}

// ---- gather2 + relu + final dot with Wl, bias bl ----
__global__ void k_gather2(const float* __restrict__ h2s, const int* __restrict__ col,
                          const int* __restrict__ rp, const float* __restrict__ dinv,
                          const float* __restrict__ b2, const float* __restrict__ Wl,
                          const float* __restrict__ bl, float* __restrict__ out, int N) {
    int t = blockIdx.x * TPB + threadIdx.x;
    int v = t >> 5;
    if (v >= N) return;
    int l32 = threadIdx.x & 31;
    int slot = l32 >> 2;                 // 0..7
    int f4 = l32 & 3;                    // features f4*4 .. f4*4+3
    int beg = rp[v], end = rp[v + 1];
    float4 s = make_float4(0.f, 0.f, 0.f, 0.f);
    if (slot == 0)                        // self loop
        s = *(const float4*)(h2s + (long long)v * 16 + f4 * 4);
    for (int i = beg + slot; i < end; i += 8) {
        int u = col[i];
        float4 a = *(const float4*)(h2s + (long long)u * 16 + f4 * 4);
        f4add(s, a);
    }
    s.x += __shfl_xor(s.x, 4);  s.y += __shfl_xor(s.y, 4);
    s.z += __shfl_xor(s.z, 4);  s.w += __shfl_xor(s.w, 4);
    s.x += __shfl_xor(s.x, 8);  s.y += __shfl_xor(s.y, 8);
    s.z += __shfl_xor(s.z, 8);  s.w += __shfl_xor(s.w, 8);
    s.x += __shfl_xor(s.x, 16); s.y += __shfl_xor(s.y, 16);
    s.z += __shfl_xor(s.z, 16); s.w += __shfl_xor(s.w, 16);
    if (slot == 0) {
        float dv = dinv[v];
        float4 bb = *(const float4*)(b2 + f4 * 4);
        float4 wl = *(const float4*)(Wl + f4 * 4);
        float rx = dv * s.x + bb.x; rx = rx > 0.f ? rx : 0.f;
        float ry = dv * s.y + bb.y; ry = ry > 0.f ? ry : 0.f;
        float rz = dv * s.z + bb.z; rz = rz > 0.f ? rz : 0.f;
        float rw = dv * s.w + bb.w; rw = rw > 0.f ? rw : 0.f;
        float p = rx * wl.x + ry * wl.y + rz * wl.z + rw * wl.w;
        p += __shfl_xor(p, 1);
        p += __shfl_xor(p, 2);
        if (f4 == 0) out[v] = p + bl[0];
    }
}

// ---------------------------------------------------------------------------
extern "C" void kernel_launch(void* const* d_in, const int* in_sizes, int n_in,
                              void* d_out, int out_size, void* d_ws, size_t ws_size,
                              hipStream_t stream) {
    const float* x    = (const float*)d_in[0];
    const int*   edges= (const int*)d_in[1];     // int32 or int64(low-word) — autodetected
    const float* W1   = (const float*)d_in[2];
    const float* b1   = (const float*)d_in[3];
    const float* W2   = (const float*)d_in[4];
    const float* b2   = (const float*)d_in[5];
    const float* Wl   = (const float*)d_in[6];
    const float* bl   = (const float*)d_in[7];
    float* out = (float*)d_out;

    const int       N = in_sizes[0] / 128;          // 100000
    const long long E = (long long)in_sizes[1] / 2; // 3200000
    const int    nbkt = (N + BKT_NODES - 1) >> BKT_SHIFT;  // 98 (<=MAXBKT)
    const int      NH = nbkt * NBLK;                // 50176
    const int    NB_H = (NH + TPB - 1) / TPB;       // 196 (<=512 for scan_top)

    // workspace layout (256B aligned slices); tmp aliases h1s region
    char* ws = (char*)d_ws;
    size_t off = 0;
    auto carve = [&](size_t bytes) { void* p = ws + off; off = (off + bytes + 255) & ~(size_t)255; return p; };
    float* dinv    = (float*)carve((size_t)N * 4);
    int*   row_ptr = (int*)  carve((size_t)(N + 1) * 4);
    int*   partialH= (int*)  carve((size_t)(NB_H + 1) * 4);
    int*   hist    = (int*)  carve((size_t)NH * 4);
    int*   histoff = (int*)  carve((size_t)(NH + 1) * 4);
    int*   col     = (int*)  carve((size_t)E * 4);
    float* unionA  = (float*)carve((size_t)N * 64 * 4);  // h1s(32)+out1(32) / packed tmp(E)
    float* h2s     = (float*)carve((size_t)N * 16 * 4);
    (void)ws_size; // total ~46 MB

    float*        h1s  = unionA;                  // N*32 floats
    float*        out1 = unionA + (size_t)N * 32;
    unsigned int* tmp  = (unsigned int*)unionA;   // E u32 (= N*32*4 bytes), dead before proj1

    // ---- binned CSR build ----
    hipLaunchKernelGGL(k_hist, dim3(NBLK), dim3(TPB), 0, stream, edges, hist, E, nbkt);
    hipLaunchKernelGGL(k_scan_partial, dim3(NB_H), dim3(TPB), 0, stream, hist, partialH, NH);
    hipLaunchKernelGGL(k_scan_top, dim3(1), dim3(512), 0, stream, partialH, NB_H);
    hipLaunchKernelGGL(k_scan_write, dim3(NB_H + 1), dim3(TPB), 0, stream, hist, partialH, histoff, NH, NB_H);
    hipLaunchKernelGGL(k_reorder, dim3(NBLK), dim3(TPB), 0, stream, edges, histoff, tmp, E, nbkt);
    hipLaunchKernelGGL(k_sortbucket, dim3(nbkt), dim3(512), 0, stream, tmp, histoff, dinv, row_ptr, col, N, E, nbkt);
    // ---- layer 1 (h1s/out1 reuse tmp region — tmp dead after sortbucket) ----
    hipLaunchKernelGGL(k_proj1, dim3((N + 63) / 64), dim3(TPB), 0, stream, x, W1, dinv, h1s, N);
    hipLaunchKernelGGL(k_gather1, dim3((N * 32 + TPB - 1) / TPB), dim3(TPB), 0, stream, h1s, col, row_ptr, dinv, b1, out1, N);
    // ---- layer 2 + head ----
    hipLaunchKernelGGL(k_proj2, dim3((N + 63) / 64), dim3(TPB), 0, stream, out1, W2, dinv, h2s, N);
    hipLaunchKernelGGL(k_gather2, dim3((N * 32 + TPB - 1) / TPB), dim3(TPB), 0, stream, h2s, col, row_ptr, dinv, b2, Wl, bl, out, N);
}